// Round 2
// baseline (5439.835 us; speedup 1.0000x reference)
//
#include <hip/hip_runtime.h>

// Bidirectional masked LSTM encoder, MI355X gfx950.
// V=50000 E=300 H=256 T=512 B=64.
// Phases: pack U/W/x into MFMA fragment order -> LDS-free bf16 MFMA GEMM for
// x@W+b (output stored bf16) -> 8 persistent blocks (4 batch-groups x 2 dirs)
// run the 512-step recurrence with MFMA 16x16x32_bf16, h dbuf in swizzled LDS.
// All final outputs written as f32 (reference output dtype).

#define T_ 512
#define B_ 64
#define E_ 300
#define FOURH 1024

typedef float floatx4 __attribute__((ext_vector_type(4)));
typedef __bf16 bf16x8 __attribute__((ext_vector_type(8)));

// ws layout (bytes):
//   xp    (bf16): 2*32768*1024*2 = 134217728   @ 0
//   xpack (bf16): 2048*10*64*8*2 =  20971520   @ 134217728
//   wp    (bf16): 2*64*10*64*8*2 =   1310720   @ 155189248
//   up    (bf16): 2*64*8*64*8*2  =   1048576   @ 156499968
// total 157548544 B (~150 MiB)
#define WS_XPACK_OFF 134217728ull
#define WS_WP_OFF    155189248ull
#define WS_UP_OFF    156499968ull
#define WS_NEEDED    157548544ull

#define OUT_H_OFF    16777216u
#define OUT_C_OFF    16809984u
#define OUT_M_OFF    16842752u

__device__ __forceinline__ unsigned short f2bf(float f) {
    unsigned int u = __builtin_bit_cast(unsigned int, f);
    u += 0x7fffu + ((u >> 16) & 1u);
    return (unsigned short)(u >> 16);
}
__device__ __forceinline__ float bf2f(unsigned short b) {
    unsigned int u = ((unsigned int)b) << 16;
    return __builtin_bit_cast(float, u);
}

__device__ __forceinline__ float sigf(float x) { return 1.f / (1.f + __expf(-x)); }

__device__ __forceinline__ float tanh_fast(float x) {
    float t = __expf(-2.f * fabsf(x));      // in (0,1], no overflow
    float r = (1.f - t) / (1.f + t);
    return x >= 0.f ? r : -r;
}

// ---------------- pack embedded x into A-fragment order --------------------
// xpack[mtile][ks][lane][8] bf16 ; row = mtile*16 + (l&15), k = ks*32 + (l>>4)*8 + e
// row r = t*64 + b  (time-major rows of xt[t][b])
__global__ void pack_x_kernel(const int* __restrict__ seq, const float* __restrict__ emb,
                              unsigned short* __restrict__ xpack) {
    const int mtile = blockIdx.x;   // 0..2047
    const int l = threadIdx.x;      // 0..63
    const int row = mtile * 16 + (l & 15);
    const int t = row >> 6, b = row & 63;
    const int token = seq[b * T_ + t];
    const float* src = emb + (size_t)token * E_;
    const int kb = (l >> 4) * 8;
#pragma unroll
    for (int ks = 0; ks < 10; ++ks) {
        const int k0 = ks * 32 + kb;
        unsigned int w[4];
#pragma unroll
        for (int h = 0; h < 4; ++h) {
            int ka = k0 + 2 * h, kbb = ka + 1;
            float fa = (ka < E_) ? src[ka] : 0.f;
            float fb = (kbb < E_) ? src[kbb] : 0.f;
            w[h] = (unsigned int)f2bf(fa) | ((unsigned int)f2bf(fb) << 16);
        }
        uint4* dst = reinterpret_cast<uint4*>(xpack + ((size_t)(mtile * 10 + ks) * 64 + l) * 8);
        *dst = make_uint4(w[0], w[1], w[2], w[3]);
    }
}

// ------------- pack a [Ksrc x 1024] f32 matrix into B-fragment order -------
// dst[ntile][ks][lane][8] ; n = ntile*16 + (l&15), k = ks*32 + (l>>4)*8 + e
__global__ void pack_mat_kernel(const float* __restrict__ src, unsigned short* __restrict__ dst,
                                int Ksrc, int nks) {
    const int ks = blockIdx.x;      // 0..nks-1
    const int ntile = blockIdx.y;   // 0..63
    const int l = threadIdx.x;
    const int n = ntile * 16 + (l & 15);
    const int k0 = ks * 32 + (l >> 4) * 8;
    unsigned int w[4];
#pragma unroll
    for (int h = 0; h < 4; ++h) {
        int ka = k0 + 2 * h, kb2 = ka + 1;
        float fa = (ka < Ksrc) ? src[(size_t)ka * FOURH + n] : 0.f;
        float fb = (kb2 < Ksrc) ? src[(size_t)kb2 * FOURH + n] : 0.f;
        w[h] = (unsigned int)f2bf(fa) | ((unsigned int)f2bf(fb) << 16);
    }
    uint4* d = reinterpret_cast<uint4*>(dst + ((size_t)(ntile * nks + ks) * 64 + l) * 8);
    *d = make_uint4(w[0], w[1], w[2], w[3]);
}

// ---------------- xproj = xpack @ Wpack + bias  (LDS-free MFMA GEMM) -------
// grid: 2 dirs * 256 mblocks * 8 nblocks ; block 256 thr = 4 waves (2x2),
// each wave 4x4 tiles of 16x16 -> block computes 128x128 of [32768 x 1024].
// Output xp stored bf16, row-major [row=t*64+b][col].
__global__ __launch_bounds__(256) void gemm_xproj_kernel(
    const unsigned short* __restrict__ xpack, const unsigned short* __restrict__ wp,
    const float* __restrict__ b_fw, const float* __restrict__ b_bw,
    unsigned short* __restrict__ xp) {
    const int bid = blockIdx.x;
    const int dir = bid >> 11;          // 2048 blocks per dir
    const int rem = bid & 2047;
    const int mb = rem >> 3;            // 0..255
    const int nb = rem & 7;             // 0..7
    const int w = threadIdx.x >> 6;
    const int l = threadIdx.x & 63;
    const int wm = w >> 1, wn = w & 1;
    const unsigned short* wpd = wp + (size_t)dir * (64 * 10 * 64 * 8);
    const float* bias = dir ? b_bw : b_fw;

    floatx4 acc[4][4];
#pragma unroll
    for (int i = 0; i < 4; ++i)
#pragma unroll
        for (int j = 0; j < 4; ++j) acc[i][j] = floatx4{0.f, 0.f, 0.f, 0.f};

#pragma unroll
    for (int ks = 0; ks < 10; ++ks) {
        bf16x8 a[4], bb[4];
#pragma unroll
        for (int mi = 0; mi < 4; ++mi) {
            int mt = mb * 8 + wm * 4 + mi;
            a[mi] = *reinterpret_cast<const bf16x8*>(xpack + ((size_t)(mt * 10 + ks) * 64 + l) * 8);
        }
#pragma unroll
        for (int ni = 0; ni < 4; ++ni) {
            int nt = nb * 8 + wn * 4 + ni;
            bb[ni] = *reinterpret_cast<const bf16x8*>(wpd + ((size_t)(nt * 10 + ks) * 64 + l) * 8);
        }
#pragma unroll
        for (int mi = 0; mi < 4; ++mi)
#pragma unroll
            for (int ni = 0; ni < 4; ++ni)
                acc[mi][ni] = __builtin_amdgcn_mfma_f32_16x16x32_bf16(a[mi], bb[ni], acc[mi][ni], 0, 0, 0);
    }

    unsigned short* xpd = xp + (size_t)dir * 33554432ull;
#pragma unroll
    for (int mi = 0; mi < 4; ++mi) {
        int mt = mb * 8 + wm * 4 + mi;
#pragma unroll
        for (int ni = 0; ni < 4; ++ni) {
            int nt = nb * 8 + wn * 4 + ni;
            int col = nt * 16 + (l & 15);
            float bv = bias[col];
#pragma unroll
            for (int e = 0; e < 4; ++e) {
                int row = mt * 16 + (l >> 4) * 4 + e;   // C/D: col=lane&15, row=(lane>>4)*4+reg
                xpd[(size_t)row * 1024 + col] = f2bf(acc[mi][ni][e] + bv);
            }
        }
    }
}

// ---------------- recurrent LSTM: 8 blocks (4 bgroups x 2 dirs) ------------
// block = 512 thr = 8 waves; wave w owns cell cols [w*32, w*32+32).
// Per step: z[16,1024] = xp + h@U via 512 MFMA/block; h dbuf in swizzled LDS.
__global__ __launch_bounds__(512) void lstm_rec_kernel(
    const int* __restrict__ seq, const unsigned short* __restrict__ xp,
    const unsigned short* __restrict__ up, float* __restrict__ out) {
    const int blk = blockIdx.x;     // 0..7
    const int dir = blk >> 2;
    const int bg = blk & 3;
    const int tid = threadIdx.x;
    const int w = tid >> 6;         // 0..7
    const int l = tid & 63;
    const unsigned short* xpd = xp + (size_t)dir * 33554432ull;
    const unsigned short* upd = up + (size_t)dir * (64 * 8 * 64 * 8);

    __shared__ __align__(16) unsigned short hbuf[2][16 * 256];
    for (int i = tid; i < 16 * 256; i += 512) hbuf[0][i] = 0;
    __syncthreads();

    const int rrb = (l >> 4) * 4;   // batch-local row base (rows rrb..rrb+3)
    int col[2];
    col[0] = (2 * w + 0) * 16 + (l & 15);
    col[1] = (2 * w + 1) * 16 + (l & 15);

    float c_s[2][4], h_s[2][4];
#pragma unroll
    for (int q = 0; q < 2; ++q)
#pragma unroll
        for (int e = 0; e < 4; ++e) { c_s[q][e] = 0.f; h_s[q][e] = 0.f; }

    // A-fragment geometry: row = l&15, k = ks*32 + (l>>4)*8, XOR-swizzled
    const int arow = l & 15;
    const int akb = (l >> 4) * 8;
    const int axor = (arow & 7) << 3;   // ushort-unit xor on k index (byte ^ (row&7)<<4)

    // prefetch xp + tokens for step 0
    float xq[2][4][4];
    int tok[4];
    {
        int t0 = dir ? 511 : 0;
        const unsigned short* xrow = xpd + (size_t)t0 * 65536 + (size_t)(bg * 16 + rrb) * 1024;
#pragma unroll
        for (int q = 0; q < 2; ++q)
#pragma unroll
            for (int g = 0; g < 4; ++g)
#pragma unroll
                for (int e = 0; e < 4; ++e)
                    xq[q][g][e] = bf2f(xrow[(size_t)e * 1024 + g * 256 + col[q]]);
#pragma unroll
        for (int e = 0; e < 4; ++e) tok[e] = seq[(bg * 16 + rrb + e) * T_ + t0];
    }

    int p = 0;
    for (int s = 0; s < 512; ++s) {
        const int t = dir ? (511 - s) : s;

        floatx4 acc[2][4];
#pragma unroll
        for (int q = 0; q < 2; ++q)
#pragma unroll
            for (int g = 0; g < 4; ++g) {
                floatx4 v;
                v[0] = xq[q][g][0]; v[1] = xq[q][g][1]; v[2] = xq[q][g][2]; v[3] = xq[q][g][3];
                acc[q][g] = v;
            }
        int tok_c[4];
#pragma unroll
        for (int e = 0; e < 4; ++e) tok_c[e] = tok[e];

        // A-fragments (h of previous step) from LDS
        bf16x8 a[8];
#pragma unroll
        for (int ks = 0; ks < 8; ++ks) {
            int k = ks * 32 + akb;
            a[ks] = *reinterpret_cast<const bf16x8*>(&hbuf[p][arow * 256 + (k ^ axor)]);
        }

        // z += h @ U  (per wave: 2 jt x 4 gates x 8 ksteps = 64 MFMA)
#pragma unroll
        for (int g = 0; g < 4; ++g) {
#pragma unroll
            for (int q = 0; q < 2; ++q) {
                int ntile = g * 16 + 2 * w + q;
                const unsigned short* ub = upd + (size_t)ntile * 4096 + (size_t)l * 8;
#pragma unroll
                for (int ks = 0; ks < 8; ++ks) {
                    bf16x8 bf = *reinterpret_cast<const bf16x8*>(ub + (size_t)ks * 512);
                    acc[q][g] = __builtin_amdgcn_mfma_f32_16x16x32_bf16(a[ks], bf, acc[q][g], 0, 0, 0);
                }
            }
        }

        // prefetch next step's xp + tokens (hides HBM latency under gates/barrier)
        if (s + 1 < 512) {
            int tn = dir ? (511 - (s + 1)) : (s + 1);
            const unsigned short* xrow = xpd + (size_t)tn * 65536 + (size_t)(bg * 16 + rrb) * 1024;
#pragma unroll
            for (int q = 0; q < 2; ++q)
#pragma unroll
                for (int g = 0; g < 4; ++g)
#pragma unroll
                    for (int e = 0; e < 4; ++e)
                        xq[q][g][e] = bf2f(xrow[(size_t)e * 1024 + g * 256 + col[q]]);
#pragma unroll
            for (int e = 0; e < 4; ++e) tok[e] = seq[(bg * 16 + rrb + e) * T_ + tn];
        }

        // gates + masked state update + writes
#pragma unroll
        for (int q = 0; q < 2; ++q) {
#pragma unroll
            for (int e = 0; e < 4; ++e) {
                float zi = acc[q][0][e];
                float zf = acc[q][1][e];
                float zg = acc[q][2][e];
                float zo = acc[q][3][e];
                float ig = sigf(zi);
                float fg = sigf(zf);
                float gg = tanh_fast(zg);
                float og = sigf(zo);
                float cn = fg * c_s[q][e] + ig * gg;
                float hn = og * tanh_fast(cn);
                if (tok_c[e] != 0) { c_s[q][e] = cn; h_s[q][e] = hn; }
                int rr = rrb + e;
                hbuf[p ^ 1][rr * 256 + (col[q] ^ ((rr & 7) << 3))] = f2bf(h_s[q][e]);
                int b = bg * 16 + rr;
                out[((size_t)(b * T_ + t)) * 512 + dir * 256 + col[q]] = h_s[q][e];
            }
        }
        __syncthreads();
        p ^= 1;
    }

    // final carried states
#pragma unroll
    for (int q = 0; q < 2; ++q)
#pragma unroll
        for (int e = 0; e < 4; ++e) {
            int b = bg * 16 + rrb + e;
            out[OUT_H_OFF + (size_t)b * 512 + dir * 256 + col[q]] = h_s[q][e];
            out[OUT_C_OFF + (size_t)b * 512 + dir * 256 + col[q]] = c_s[q][e];
        }
}

// ---------------- mask output ----------------------------------------------
__global__ void mask_kernel(const int* __restrict__ seq, float* __restrict__ out) {
    int i = blockIdx.x * 256 + threadIdx.x;
    if (i < B_ * T_) out[OUT_M_OFF + i] = (seq[i] != 0) ? 1.0f : 0.0f;
}

extern "C" void kernel_launch(void* const* d_in, const int* in_sizes, int n_in,
                              void* d_out, int out_size, void* d_ws, size_t ws_size,
                              hipStream_t stream) {
    const int* seq = (const int*)d_in[0];
    // d_in[1]=state_h0, d_in[2]=state_c0: unused by the reference (zero init)
    const float* emb  = (const float*)d_in[3];
    const float* W_fw = (const float*)d_in[4];
    const float* U_fw = (const float*)d_in[5];
    const float* b_fw = (const float*)d_in[6];
    const float* W_bw = (const float*)d_in[7];
    const float* U_bw = (const float*)d_in[8];
    const float* b_bw = (const float*)d_in[9];
    float* out = (float*)d_out;

    // Always produce the mask (writes only to d_out).
    hipLaunchKernelGGL(mask_kernel, dim3(128), dim3(256), 0, stream, seq, out);

    if (ws_size < WS_NEEDED) {
        // Workspace too small for the staged pipeline: bail out cleanly
        // (diagnostic: outputs 0..2 stay zero/poison -> distinctive absmax).
        return;
    }

    char* ws = (char*)d_ws;
    unsigned short* xp    = (unsigned short*)ws;
    unsigned short* xpack = (unsigned short*)(ws + WS_XPACK_OFF);
    unsigned short* wp    = (unsigned short*)(ws + WS_WP_OFF);
    unsigned short* up    = (unsigned short*)(ws + WS_UP_OFF);

    hipLaunchKernelGGL(pack_x_kernel, dim3(2048), dim3(64), 0, stream, seq, emb, xpack);
    hipLaunchKernelGGL(pack_mat_kernel, dim3(10, 64), dim3(64), 0, stream, W_fw, wp,          300, 10);
    hipLaunchKernelGGL(pack_mat_kernel, dim3(10, 64), dim3(64), 0, stream, W_bw, wp + 327680, 300, 10);
    hipLaunchKernelGGL(pack_mat_kernel, dim3(8, 64),  dim3(64), 0, stream, U_fw, up,          256, 8);
    hipLaunchKernelGGL(pack_mat_kernel, dim3(8, 64),  dim3(64), 0, stream, U_bw, up + 262144, 256, 8);
    hipLaunchKernelGGL(gemm_xproj_kernel, dim3(4096), dim3(256), 0, stream, xpack, wp, b_fw, b_bw, xp);
    hipLaunchKernelGGL(lstm_rec_kernel, dim3(8), dim3(512), 0, stream, seq, xp, up, out);
}